// Round 7
// baseline (574.050 us; speedup 1.0000x reference)
//
#include <hip/hip_runtime.h>
#include <math.h>

#define N_NODES 100000
#define N_EDGES 600000
#define NC 41
#define NT (N_NODES / 16)            // 6250 exact 16-node tiles
#define NB ((N_NODES + 255) / 256)   // scan blocks
#define SRCM 0x07FFFFFF

typedef __attribute__((ext_vector_type(8))) short bf16x8;
typedef __attribute__((ext_vector_type(8))) unsigned short u16x8;
typedef __attribute__((ext_vector_type(4))) float f32x4;

static __device__ __forceinline__ unsigned short f2b(float f) {
    unsigned u = __float_as_uint(f);
    unsigned r = ((u >> 16) & 1u) + 0x7fffu;
    return (unsigned short)((u + r) >> 16);
}
static __device__ __forceinline__ float b2f(unsigned short s) {
    return __uint_as_float(((unsigned)s) << 16);
}
static __device__ __forceinline__ u16x8 zero8() {
    u16x8 z;
#pragma unroll
    for (int i = 0; i < 8; ++i) z[i] = 0;
    return z;
}

// ---------- CSR build ----------
__global__ void k_count(const int* __restrict__ dst, int* __restrict__ cnt, int E) {
    int e = blockIdx.x * blockDim.x + threadIdx.x;
    if (e < E) atomicAdd(&cnt[dst[e]], 1);
}

__global__ __launch_bounds__(256) void k_blocksum(const int* __restrict__ cnt,
                                                  int* __restrict__ bsum,
                                                  float* __restrict__ dinv, int n) {
    __shared__ int tmp[256];
    int t = threadIdx.x, gid = blockIdx.x * 256 + t;
    int v = (gid < n) ? cnt[gid] : 0;
    if (gid < n) dinv[gid] = rsqrtf((float)(v + 1));  // +1 self-loop
    tmp[t] = v;
    __syncthreads();
    for (int d = 128; d; d >>= 1) {
        if (t < d) tmp[t] += tmp[t + d];
        __syncthreads();
    }
    if (t == 0) bsum[blockIdx.x] = tmp[0];
}

__global__ __launch_bounds__(512) void k_scanb(int* __restrict__ bsum, int nb) {
    __shared__ int tmp[512];
    int t = threadIdx.x;
    int v = (t < nb) ? bsum[t] : 0;
    tmp[t] = v;
    __syncthreads();
    for (int d = 1; d < 512; d <<= 1) {
        int u = (t >= d) ? tmp[t - d] : 0;
        __syncthreads();
        tmp[t] += u;
        __syncthreads();
    }
    if (t < nb) bsum[t] = tmp[t] - v;
}

__global__ __launch_bounds__(256) void k_scanfinal(int* __restrict__ cnt,
                                                   const int* __restrict__ bsum,
                                                   int* __restrict__ off, int n) {
    __shared__ int tmp[256];
    int t = threadIdx.x, gid = blockIdx.x * 256 + t;
    int v = (gid < n) ? cnt[gid] : 0;
    tmp[t] = v;
    __syncthreads();
    for (int d = 1; d < 256; d <<= 1) {
        int u = (t >= d) ? tmp[t - d] : 0;
        __syncthreads();
        tmp[t] += u;
        __syncthreads();
    }
    int ex = tmp[t] - v + bsum[blockIdx.x];
    if (gid < n) {
        off[gid] = ex;
        cnt[gid] = ex;
    }
    if (gid == 0) off[n] = N_EDGES;
}

// scatter: pack src (27b) + local dst (4b, tile=16) into one int
__global__ void k_scatter(const int* __restrict__ src, const int* __restrict__ dst,
                          int* __restrict__ cursor, int* __restrict__ eidx, int E) {
    int e = blockIdx.x * blockDim.x + threadIdx.x;
    if (e >= E) return;
    int d = dst[e];
    int pos = atomicAdd(&cursor[d], 1);
    eidx[pos] = src[e] | ((d & 15) << 27);
}

// ---------- GEMM1 (MFMA): h1' = dinv[r] * (bf16(x) @ bf16(W1)), bf16 out ----------
__global__ __launch_bounds__(256) void k_gemm1(const float* __restrict__ x,
                                               const float* __restrict__ W,
                                               const float* __restrict__ dinv,
                                               unsigned short* __restrict__ h) {
    __shared__ unsigned short Wt[128 * 132];  // [n][k], padded
    int tid = threadIdx.x;
    for (int i = tid; i < 128 * 128; i += 256) {
        int k = i >> 7, n = i & 127;
        Wt[n * 132 + k] = f2b(W[i]);
    }
    __syncthreads();

    int l = tid & 63, w = tid >> 6;
    int lr = l & 15, g = l >> 4;

    bf16x8 bf[2][4];
#pragma unroll
    for (int c = 0; c < 2; ++c) {
        int n = (w * 2 + c) * 16 + lr;
#pragma unroll
        for (int kt = 0; kt < 4; ++kt) {
            const unsigned short* p = &Wt[n * 132 + kt * 32 + g * 4];
            short4 lo = *(const short4*)p;
            short4 hi = *(const short4*)(p + 16);
            bf16x8 f;
            f[0] = lo.x; f[1] = lo.y; f[2] = lo.z; f[3] = lo.w;
            f[4] = hi.x; f[5] = hi.y; f[6] = hi.z; f[7] = hi.w;
            bf[c][kt] = f;
        }
    }

    for (int t = blockIdx.x; t < NT; t += gridDim.x) {
        int row = t * 16 + lr;
        const float4* xr = (const float4*)(x + (size_t)row * 128);
        f32x4 acc0 = {0.f, 0.f, 0.f, 0.f};
        f32x4 acc1 = {0.f, 0.f, 0.f, 0.f};
#pragma unroll
        for (int kt = 0; kt < 4; ++kt) {
            float4 alo = xr[kt * 8 + g];
            float4 ahi = xr[kt * 8 + 4 + g];
            bf16x8 a;
            a[0] = (short)f2b(alo.x); a[1] = (short)f2b(alo.y);
            a[2] = (short)f2b(alo.z); a[3] = (short)f2b(alo.w);
            a[4] = (short)f2b(ahi.x); a[5] = (short)f2b(ahi.y);
            a[6] = (short)f2b(ahi.z); a[7] = (short)f2b(ahi.w);
            acc0 = __builtin_amdgcn_mfma_f32_16x16x32_bf16(a, bf[0][kt], acc0, 0, 0, 0);
            acc1 = __builtin_amdgcn_mfma_f32_16x16x32_bf16(a, bf[1][kt], acc1, 0, 0, 0);
        }
        int c0 = (w * 2) * 16 + lr;
        int rbase = t * 16 + g * 4;
#pragma unroll
        for (int i = 0; i < 4; ++i) {
            float dv = dinv[rbase + i];
            h[(size_t)(rbase + i) * 128 + c0] = f2b(acc0[i] * dv);
            h[(size_t)(rbase + i) * 128 + c0 + 16] = f2b(acc1[i] * dv);
        }
    }
}

// ---------- fused agg1 + GEMM2, EDGE-PARALLEL ----------
// Tile = 16 nodes -> contiguous CSR edge range. Each 16-lane group handles one
// edge per step (2-unrolled): load 256B row, ds_add_f32 into LDS f32 tile.
// No per-node serial chain, no degree divergence. Then self+bias+relu -> bf16
// staging -> 16x48 MFMA with W2.
__global__ __launch_bounds__(256, 6) void k_agg1mm(const unsigned short* __restrict__ h,
                                                   const float* __restrict__ W2,
                                                   const float* __restrict__ dinv,
                                                   const float* __restrict__ b1,
                                                   const int* __restrict__ off,
                                                   const int* __restrict__ eidx,
                                                   unsigned short* __restrict__ h2) {
    __shared__ unsigned short Wt[48 * 132];   // W2^T bf16, padded
    __shared__ float accf[16 * 132];          // f32 accumulation tile
    __shared__ unsigned short rows[16 * 136]; // bf16 staged rows for MFMA
    int tid = threadIdx.x;
    for (int i = tid; i < 128 * 48; i += 256) {
        int k = i / 48, n = i % 48;
        Wt[n * 132 + k] = f2b((n < NC) ? W2[k * NC + n] : 0.f);
    }

    int l = tid & 63, w = tid >> 6;
    int grp = l >> 4, j = l & 15;
    int nloc = w * 4 + grp;
    int lr = l & 15, g = l >> 4;

    for (int t = blockIdx.x; t < NT; t += gridDim.x) {
        for (int i = tid; i < 16 * 132; i += 256) accf[i] = 0.f;
        __syncthreads();

        int beg = off[t * 16], end = off[t * 16 + 16];
        for (int e0 = beg; e0 < end; e0 += 32) {
            int ea = e0 + w * 8 + grp * 2;
            int eb = ea + 1;
            int pka = (ea < end) ? eidx[ea] : -1;
            int pkb = (eb < end) ? eidx[eb] : -1;
            u16x8 ra = zero8(), rb = zero8();
            int la = 0, lb = 0;
            if (pka >= 0) {
                la = (pka >> 27) & 15;
                ra = *(const u16x8*)(h + (size_t)(pka & SRCM) * 128 + j * 8);
            }
            if (pkb >= 0) {
                lb = (pkb >> 27) & 15;
                rb = *(const u16x8*)(h + (size_t)(pkb & SRCM) * 128 + j * 8);
            }
            if (pka >= 0) {
                float* base = &accf[la * 132 + j * 8];
#pragma unroll
                for (int i = 0; i < 8; ++i) {
                    int ii = (i + j) & 7;  // rotate: <=2-way LDS bank aliasing
                    unsafeAtomicAdd(&base[ii], b2f(ra[ii]));
                }
            }
            if (pkb >= 0) {
                float* base = &accf[lb * 132 + j * 8];
#pragma unroll
                for (int i = 0; i < 8; ++i) {
                    int ii = (i + j) & 7;
                    unsafeAtomicAdd(&base[ii], b2f(rb[ii]));
                }
            }
        }
        __syncthreads();

        // epilogue: self-loop + bias + relu -> bf16 staging
        {
            int node = t * 16 + nloc;
            float di = dinv[node];
            u16x8 v = *(const u16x8*)(h + (size_t)node * 128 + j * 8);
            float4 blo = ((const float4*)b1)[j * 2];
            float4 bhi = ((const float4*)b1)[j * 2 + 1];
            float bb[8] = {blo.x, blo.y, blo.z, blo.w, bhi.x, bhi.y, bhi.z, bhi.w};
            u16x8 o;
#pragma unroll
            for (int i = 0; i < 8; ++i) {
                float a = accf[nloc * 132 + j * 8 + i] + b2f(v[i]);
                o[i] = f2b(fmaxf(a * di + bb[i], 0.f));
            }
            *(u16x8*)&rows[nloc * 136 + j * 8] = o;
        }
        __syncthreads();

        if (w < 3) {  // col-tile w of 3 (48 cols)
            f32x4 a0 = {0.f, 0.f, 0.f, 0.f};
#pragma unroll
            for (int kt = 0; kt < 4; ++kt) {
                const unsigned short* pa = &rows[lr * 136 + kt * 32 + g * 4];
                short4 alo = *(const short4*)pa;
                short4 ahi = *(const short4*)(pa + 16);
                bf16x8 a;
                a[0] = alo.x; a[1] = alo.y; a[2] = alo.z; a[3] = alo.w;
                a[4] = ahi.x; a[5] = ahi.y; a[6] = ahi.z; a[7] = ahi.w;
                const unsigned short* pb = &Wt[(w * 16 + lr) * 132 + kt * 32 + g * 4];
                short4 wlo = *(const short4*)pb;
                short4 whi = *(const short4*)(pb + 16);
                bf16x8 b;
                b[0] = wlo.x; b[1] = wlo.y; b[2] = wlo.z; b[3] = wlo.w;
                b[4] = whi.x; b[5] = whi.y; b[6] = whi.z; b[7] = whi.w;
                a0 = __builtin_amdgcn_mfma_f32_16x16x32_bf16(a, b, a0, 0, 0, 0);
            }
            int rbase = t * 16 + g * 4;
#pragma unroll
            for (int i = 0; i < 4; ++i) {
                float dv = dinv[rbase + i];
                h2[(size_t)(rbase + i) * 64 + w * 16 + lr] = f2b(a0[i] * dv);
            }
        }
        __syncthreads();
    }
}

// ---------- gather2: out = log_softmax(di * (self + sum h2'[s]) + b2) ----------
// 2 nodes per wave; 4 groups x 8 lanes per node; 2-deep row prefetch.
__global__ __launch_bounds__(256, 8) void k_gather2(const unsigned short* __restrict__ h2,
                                                    float* __restrict__ out,
                                                    const int* __restrict__ off,
                                                    const int* __restrict__ eidx,
                                                    const float* __restrict__ dinv,
                                                    const float* __restrict__ b2, int N) {
    int node = blockIdx.x * 8 + (threadIdx.x >> 5);
    if (node >= N) return;
    int l = threadIdx.x & 31;
    int g = l >> 3, j = l & 7;
    bool act = (j < 6);
    float di = dinv[node];
    float acc[8];
#pragma unroll
    for (int i = 0; i < 8; ++i) acc[i] = 0.f;
    if (g == 0 && act) {
        u16x8 v = *(const u16x8*)(h2 + (size_t)node * 64 + j * 8);
#pragma unroll
        for (int i = 0; i < 8; ++i) acc[i] = b2f(v[i]);
    }
    int beg = off[node], end = off[node + 1];
    int e = beg + g;
    int s0 = (e < end) ? (eidx[e] & SRCM) : -1;
    int s1 = (e + 4 < end) ? (eidx[e + 4] & SRCM) : -1;
    u16x8 r0 = zero8(), r1 = zero8();
    if (s0 >= 0 && act) r0 = *(const u16x8*)(h2 + (size_t)s0 * 64 + j * 8);
    if (s1 >= 0 && act) r1 = *(const u16x8*)(h2 + (size_t)s1 * 64 + j * 8);
    while (s0 >= 0) {
        int s2 = (e + 8 < end) ? (eidx[e + 8] & SRCM) : -1;
        u16x8 r2 = zero8();
        if (s2 >= 0 && act) r2 = *(const u16x8*)(h2 + (size_t)s2 * 64 + j * 8);
#pragma unroll
        for (int i = 0; i < 8; ++i) acc[i] += b2f(r0[i]);
        s0 = s1; s1 = s2; r0 = r1; r1 = r2; e += 4;
    }
#pragma unroll
    for (int i = 0; i < 8; ++i) acc[i] += __shfl_xor(acc[i], 8);
#pragma unroll
    for (int i = 0; i < 8; ++i) acc[i] += __shfl_xor(acc[i], 16);
    int c0 = j * 8;
    float vv[8];
#pragma unroll
    for (int i = 0; i < 8; ++i)
        vv[i] = (act && c0 + i < NC) ? acc[i] * di + b2[c0 + i] : -INFINITY;
    float m = vv[0];
#pragma unroll
    for (int i = 1; i < 8; ++i) m = fmaxf(m, vv[i]);
#pragma unroll
    for (int o = 4; o; o >>= 1) m = fmaxf(m, __shfl_xor(m, o));
    float sm = 0.f;
#pragma unroll
    for (int i = 0; i < 8; ++i) sm += (act && c0 + i < NC) ? expf(vv[i] - m) : 0.f;
#pragma unroll
    for (int o = 4; o; o >>= 1) sm += __shfl_xor(sm, o);
    float lg = logf(sm);
    if (g == 0 && act) {
#pragma unroll
        for (int i = 0; i < 8; ++i) {
            int c = c0 + i;
            if (c < NC) out[(size_t)node * NC + c] = vv[i] - m - lg;
        }
    }
}

extern "C" void kernel_launch(void* const* d_in, const int* in_sizes, int n_in,
                              void* d_out, int out_size, void* d_ws, size_t ws_size,
                              hipStream_t stream) {
    const float* x  = (const float*)d_in[0];
    const float* W1 = (const float*)d_in[1];
    const float* b1 = (const float*)d_in[2];
    const float* W2 = (const float*)d_in[3];
    const float* b2 = (const float*)d_in[4];
    const int*   ei = (const int*)d_in[5];
    const int* src = ei;
    const int* dst = ei + N_EDGES;
    float* out = (float*)d_out;

    char* ws = (char*)d_ws;
    int*   cnt  = (int*)ws;
    int*   off  = cnt + N_NODES + 32;
    int*   bsum = off + N_NODES + 32;
    float* dinv = (float*)(bsum + 512);
    int*   eidx = (int*)(dinv + N_NODES);
    unsigned short* h1 = (unsigned short*)(ws + (8u << 20));   // N*128 bf16 (pre-scaled)
    unsigned short* h2 = h1 + (size_t)N_NODES * 128;           // N*64 bf16 (pre-scaled)

    // CSR build
    hipMemsetAsync(cnt, 0, N_NODES * sizeof(int), stream);
    k_count<<<(N_EDGES + 255) / 256, 256, 0, stream>>>(dst, cnt, N_EDGES);
    k_blocksum<<<NB, 256, 0, stream>>>(cnt, bsum, dinv, N_NODES);
    k_scanb<<<1, 512, 0, stream>>>(bsum, NB);
    k_scanfinal<<<NB, 256, 0, stream>>>(cnt, bsum, off, N_NODES);
    k_scatter<<<(N_EDGES + 255) / 256, 256, 0, stream>>>(src, dst, cnt, eidx, N_EDGES);

    // layer 1 + layer-2 GEMM fused
    k_gemm1<<<1024, 256, 0, stream>>>(x, W1, dinv, h1);
    k_agg1mm<<<1536, 256, 0, stream>>>(h1, W2, dinv, b1, off, eidx, h2);

    // layer-2 aggregation + log_softmax
    k_gather2<<<(N_NODES + 7) / 8, 256, 0, stream>>>(h2, out, off, eidx, dinv, b2, N_NODES);
}

// Round 8
// 292.090 us; speedup vs baseline: 1.9653x; 1.9653x over previous
//
#include <hip/hip_runtime.h>
#include <hip/hip_cooperative_groups.h>
#include <math.h>

namespace cg = cooperative_groups;

#define N_NODES 100000
#define N_EDGES 600000
#define NC 41
#define NT (N_NODES / 16)            // 6250 exact 16-node tiles
#define CB 196                       // coop blocks (512 thr each covers 100352 nodes)
#define CT 512

typedef __attribute__((ext_vector_type(8))) short bf16x8;
typedef __attribute__((ext_vector_type(8))) unsigned short u16x8;
typedef __attribute__((ext_vector_type(4))) float f32x4;

static __device__ __forceinline__ unsigned short f2b(float f) {
    unsigned u = __float_as_uint(f);
    unsigned r = ((u >> 16) & 1u) + 0x7fffu;
    return (unsigned short)((u + r) >> 16);
}
static __device__ __forceinline__ float b2f(unsigned short s) {
    return __uint_as_float(((unsigned)s) << 16);
}
static __device__ __forceinline__ u16x8 zero8() {
    u16x8 z;
#pragma unroll
    for (int i = 0; i < 8; ++i) z[i] = 0;
    return z;
}

// ---------- fused CSR build: zero -> count -> dinv/blocksum -> scan -> scatter ----------
__global__ __launch_bounds__(CT) void k_csr(const int* __restrict__ src,
                                            const int* __restrict__ dst,
                                            int* __restrict__ cnt,
                                            int* __restrict__ off,
                                            int* __restrict__ bsum,
                                            float* __restrict__ dinv,
                                            int* __restrict__ eidx) {
    cg::grid_group grid = cg::this_grid();
    __shared__ int tmp[CT];
    int t = threadIdx.x, b = blockIdx.x;
    int gid = b * CT + t;
    const int nthr = CB * CT;

    // zero counts
    for (int i = gid; i < N_NODES; i += nthr) cnt[i] = 0;
    grid.sync();

    // degree count
    for (int e = gid; e < N_EDGES; e += nthr) atomicAdd(&cnt[dst[e]], 1);
    grid.sync();

    // dinv + per-block sum
    int v = (gid < N_NODES) ? cnt[gid] : 0;
    if (gid < N_NODES) dinv[gid] = rsqrtf((float)(v + 1));  // +1 self-loop
    tmp[t] = v;
    __syncthreads();
    for (int d = CT / 2; d; d >>= 1) {
        if (t < d) tmp[t] += tmp[t + d];
        __syncthreads();
    }
    if (t == 0) bsum[b] = tmp[0];
    grid.sync();

    // exclusive scan of block sums (block 0; CB <= CT)
    if (b == 0) {
        int bv = (t < CB) ? bsum[t] : 0;
        tmp[t] = bv;
        __syncthreads();
        for (int d = 1; d < CT; d <<= 1) {
            int u = (t >= d) ? tmp[t - d] : 0;
            __syncthreads();
            tmp[t] += u;
            __syncthreads();
        }
        if (t < CB) bsum[t] = tmp[t] - bv;
    }
    grid.sync();

    // exclusive scan within block segment -> off, cursor
    tmp[t] = v;
    __syncthreads();
    for (int d = 1; d < CT; d <<= 1) {
        int u = (t >= d) ? tmp[t - d] : 0;
        __syncthreads();
        tmp[t] += u;
        __syncthreads();
    }
    int ex = tmp[t] - v + bsum[b];
    if (gid < N_NODES) {
        off[gid] = ex;
        cnt[gid] = ex;  // becomes scatter cursor
    }
    if (gid == 0) off[N_NODES] = N_EDGES;
    grid.sync();

    // scatter src indices into CSR order
    for (int e = gid; e < N_EDGES; e += nthr) {
        int d = dst[e];
        int pos = atomicAdd(&cnt[d], 1);
        eidx[pos] = src[e];
    }
}

// ---------- GEMM1 (MFMA): h1' = dinv[r] * (bf16(x) @ bf16(W1)), bf16 out ----------
__global__ __launch_bounds__(256) void k_gemm1(const float* __restrict__ x,
                                               const float* __restrict__ W,
                                               const float* __restrict__ dinv,
                                               unsigned short* __restrict__ h) {
    __shared__ unsigned short Wt[128 * 132];  // [n][k], padded
    int tid = threadIdx.x;
    for (int i = tid; i < 128 * 128; i += 256) {
        int k = i >> 7, n = i & 127;
        Wt[n * 132 + k] = f2b(W[i]);
    }
    __syncthreads();

    int l = tid & 63, w = tid >> 6;
    int lr = l & 15, g = l >> 4;

    bf16x8 bf[2][4];
#pragma unroll
    for (int c = 0; c < 2; ++c) {
        int n = (w * 2 + c) * 16 + lr;
#pragma unroll
        for (int kt = 0; kt < 4; ++kt) {
            const unsigned short* p = &Wt[n * 132 + kt * 32 + g * 4];
            short4 lo = *(const short4*)p;
            short4 hi = *(const short4*)(p + 16);
            bf16x8 f;
            f[0] = lo.x; f[1] = lo.y; f[2] = lo.z; f[3] = lo.w;
            f[4] = hi.x; f[5] = hi.y; f[6] = hi.z; f[7] = hi.w;
            bf[c][kt] = f;
        }
    }

    for (int t = blockIdx.x; t < NT; t += gridDim.x) {
        int row = t * 16 + lr;
        const float4* xr = (const float4*)(x + (size_t)row * 128);
        f32x4 acc0 = {0.f, 0.f, 0.f, 0.f};
        f32x4 acc1 = {0.f, 0.f, 0.f, 0.f};
#pragma unroll
        for (int kt = 0; kt < 4; ++kt) {
            float4 alo = xr[kt * 8 + g];
            float4 ahi = xr[kt * 8 + 4 + g];
            bf16x8 a;
            a[0] = (short)f2b(alo.x); a[1] = (short)f2b(alo.y);
            a[2] = (short)f2b(alo.z); a[3] = (short)f2b(alo.w);
            a[4] = (short)f2b(ahi.x); a[5] = (short)f2b(ahi.y);
            a[6] = (short)f2b(ahi.z); a[7] = (short)f2b(ahi.w);
            acc0 = __builtin_amdgcn_mfma_f32_16x16x32_bf16(a, bf[0][kt], acc0, 0, 0, 0);
            acc1 = __builtin_amdgcn_mfma_f32_16x16x32_bf16(a, bf[1][kt], acc1, 0, 0, 0);
        }
        int c0 = (w * 2) * 16 + lr;
        int rbase = t * 16 + g * 4;
#pragma unroll
        for (int i = 0; i < 4; ++i) {
            float dv = dinv[rbase + i];
            h[(size_t)(rbase + i) * 128 + c0] = f2b(acc0[i] * dv);
            h[(size_t)(rbase + i) * 128 + c0 + 16] = f2b(acc1[i] * dv);
        }
    }
}

// ---------- fused agg1 + GEMM2 (node-serial gather, R6 structure) ----------
__global__ __launch_bounds__(256, 8) void k_agg1mm(const unsigned short* __restrict__ h,
                                                   const float* __restrict__ W2,
                                                   const float* __restrict__ dinv,
                                                   const float* __restrict__ b1,
                                                   const int* __restrict__ off,
                                                   const int* __restrict__ eidx,
                                                   unsigned short* __restrict__ h2) {
    __shared__ unsigned short Wt[48 * 132];   // W2^T bf16, padded
    __shared__ unsigned short rows[16 * 136]; // staged agg rows, padded
    int tid = threadIdx.x;
    for (int i = tid; i < 128 * 48; i += 256) {
        int k = i / 48, n = i % 48;
        Wt[n * 132 + k] = f2b((n < NC) ? W2[k * NC + n] : 0.f);
    }
    __syncthreads();

    int l = tid & 63, w = tid >> 6;
    int j = l & 15;                 // col-slice within node (8 cols each)
    int nloc = w * 4 + (l >> 4);    // node-local 0..15
    int lr = l & 15, g = l >> 4;

    for (int t = blockIdx.x; t < NT; t += gridDim.x) {
        int node = t * 16 + nloc;
        float di = dinv[node];
        float acc[8];
        {
            u16x8 v = *(const u16x8*)(h + (size_t)node * 128 + j * 8);
#pragma unroll
            for (int i = 0; i < 8; ++i) acc[i] = b2f(v[i]);
        }
        int beg = off[node], end = off[node + 1];
        int e = beg;
        int s0 = (e < end) ? eidx[e] : -1;
        int s1 = (e + 1 < end) ? eidx[e + 1] : -1;
        u16x8 r0 = zero8(), r1 = zero8();
        if (s0 >= 0) r0 = *(const u16x8*)(h + (size_t)s0 * 128 + j * 8);
        if (s1 >= 0) r1 = *(const u16x8*)(h + (size_t)s1 * 128 + j * 8);
        while (s0 >= 0) {
            int s2 = (e + 2 < end) ? eidx[e + 2] : -1;
            u16x8 r2 = zero8();
            if (s2 >= 0) r2 = *(const u16x8*)(h + (size_t)s2 * 128 + j * 8);
#pragma unroll
            for (int i = 0; i < 8; ++i) acc[i] += b2f(r0[i]);
            s0 = s1; s1 = s2; r0 = r1; r1 = r2; ++e;
        }
        // relu(di*acc + b1) -> LDS
        float4 blo = ((const float4*)b1)[j * 2];
        float4 bhi = ((const float4*)b1)[j * 2 + 1];
        u16x8 o;
        o[0] = f2b(fmaxf(acc[0] * di + blo.x, 0.f));
        o[1] = f2b(fmaxf(acc[1] * di + blo.y, 0.f));
        o[2] = f2b(fmaxf(acc[2] * di + blo.z, 0.f));
        o[3] = f2b(fmaxf(acc[3] * di + blo.w, 0.f));
        o[4] = f2b(fmaxf(acc[4] * di + bhi.x, 0.f));
        o[5] = f2b(fmaxf(acc[5] * di + bhi.y, 0.f));
        o[6] = f2b(fmaxf(acc[6] * di + bhi.z, 0.f));
        o[7] = f2b(fmaxf(acc[7] * di + bhi.w, 0.f));
        *(u16x8*)&rows[nloc * 136 + j * 8] = o;
        __syncthreads();

        if (w < 3) {  // col-tile w of 3 (48 cols)
            f32x4 a0 = {0.f, 0.f, 0.f, 0.f};
#pragma unroll
            for (int kt = 0; kt < 4; ++kt) {
                const unsigned short* pa = &rows[lr * 136 + kt * 32 + g * 4];
                short4 alo = *(const short4*)pa;
                short4 ahi = *(const short4*)(pa + 16);
                bf16x8 a;
                a[0] = alo.x; a[1] = alo.y; a[2] = alo.z; a[3] = alo.w;
                a[4] = ahi.x; a[5] = ahi.y; a[6] = ahi.z; a[7] = ahi.w;
                const unsigned short* pb = &Wt[(w * 16 + lr) * 132 + kt * 32 + g * 4];
                short4 wlo = *(const short4*)pb;
                short4 whi = *(const short4*)(pb + 16);
                bf16x8 bb;
                bb[0] = wlo.x; bb[1] = wlo.y; bb[2] = wlo.z; bb[3] = wlo.w;
                bb[4] = whi.x; bb[5] = whi.y; bb[6] = whi.z; bb[7] = whi.w;
                a0 = __builtin_amdgcn_mfma_f32_16x16x32_bf16(a, bb, a0, 0, 0, 0);
            }
            int rbase = t * 16 + g * 4;
#pragma unroll
            for (int i = 0; i < 4; ++i) {
                float dv = dinv[rbase + i];
                h2[(size_t)(rbase + i) * 64 + w * 16 + lr] = f2b(a0[i] * dv);
            }
        }
        __syncthreads();
    }
}

// ---------- gather2: out = log_softmax(di * (self + sum h2'[s]) + b2) ----------
__global__ __launch_bounds__(256, 8) void k_gather2(const unsigned short* __restrict__ h2,
                                                    float* __restrict__ out,
                                                    const int* __restrict__ off,
                                                    const int* __restrict__ eidx,
                                                    const float* __restrict__ dinv,
                                                    const float* __restrict__ b2, int N) {
    int node = blockIdx.x * 8 + (threadIdx.x >> 5);
    if (node >= N) return;
    int l = threadIdx.x & 31;
    int g = l >> 3, j = l & 7;
    bool act = (j < 6);
    float di = dinv[node];
    float acc[8];
#pragma unroll
    for (int i = 0; i < 8; ++i) acc[i] = 0.f;
    if (g == 0 && act) {
        u16x8 v = *(const u16x8*)(h2 + (size_t)node * 64 + j * 8);
#pragma unroll
        for (int i = 0; i < 8; ++i) acc[i] = b2f(v[i]);
    }
    int beg = off[node], end = off[node + 1];
    int e = beg + g;
    int s0 = (e < end) ? eidx[e] : -1;
    int s1 = (e + 4 < end) ? eidx[e + 4] : -1;
    u16x8 r0 = zero8(), r1 = zero8();
    if (s0 >= 0 && act) r0 = *(const u16x8*)(h2 + (size_t)s0 * 64 + j * 8);
    if (s1 >= 0 && act) r1 = *(const u16x8*)(h2 + (size_t)s1 * 64 + j * 8);
    while (s0 >= 0) {
        int s2 = (e + 8 < end) ? eidx[e + 8] : -1;
        u16x8 r2 = zero8();
        if (s2 >= 0 && act) r2 = *(const u16x8*)(h2 + (size_t)s2 * 64 + j * 8);
#pragma unroll
        for (int i = 0; i < 8; ++i) acc[i] += b2f(r0[i]);
        s0 = s1; s1 = s2; r0 = r1; r1 = r2; e += 4;
    }
#pragma unroll
    for (int i = 0; i < 8; ++i) acc[i] += __shfl_xor(acc[i], 8);
#pragma unroll
    for (int i = 0; i < 8; ++i) acc[i] += __shfl_xor(acc[i], 16);
    int c0 = j * 8;
    float vv[8];
#pragma unroll
    for (int i = 0; i < 8; ++i)
        vv[i] = (act && c0 + i < NC) ? acc[i] * di + b2[c0 + i] : -INFINITY;
    float m = vv[0];
#pragma unroll
    for (int i = 1; i < 8; ++i) m = fmaxf(m, vv[i]);
#pragma unroll
    for (int o = 4; o; o >>= 1) m = fmaxf(m, __shfl_xor(m, o));
    float sm = 0.f;
#pragma unroll
    for (int i = 0; i < 8; ++i) sm += (act && c0 + i < NC) ? expf(vv[i] - m) : 0.f;
#pragma unroll
    for (int o = 4; o; o >>= 1) sm += __shfl_xor(sm, o);
    float lg = logf(sm);
    if (g == 0 && act) {
#pragma unroll
        for (int i = 0; i < 8; ++i) {
            int c = c0 + i;
            if (c < NC) out[(size_t)node * NC + c] = vv[i] - m - lg;
        }
    }
}

extern "C" void kernel_launch(void* const* d_in, const int* in_sizes, int n_in,
                              void* d_out, int out_size, void* d_ws, size_t ws_size,
                              hipStream_t stream) {
    const float* x  = (const float*)d_in[0];
    const float* W1 = (const float*)d_in[1];
    const float* b1 = (const float*)d_in[2];
    const float* W2 = (const float*)d_in[3];
    const float* b2 = (const float*)d_in[4];
    const int*   ei = (const int*)d_in[5];
    const int* src = ei;
    const int* dst = ei + N_EDGES;
    float* out = (float*)d_out;

    char* ws = (char*)d_ws;
    int*   cnt  = (int*)ws;
    int*   off  = cnt + N_NODES + 32;
    int*   bsum = off + N_NODES + 32;
    float* dinv = (float*)(bsum + 512);
    int*   eidx = (int*)(dinv + N_NODES);
    unsigned short* h1 = (unsigned short*)(ws + (8u << 20));   // N*128 bf16 (pre-scaled)
    unsigned short* h2 = h1 + (size_t)N_NODES * 128;           // N*64 bf16 (pre-scaled)

    // single-launch CSR build (cooperative)
    {
        void* args[] = {(void*)&src, (void*)&dst, (void*)&cnt, (void*)&off,
                        (void*)&bsum, (void*)&dinv, (void*)&eidx};
        hipLaunchCooperativeKernel((const void*)k_csr, dim3(CB), dim3(CT),
                                   args, 0, stream);
    }

    // layer 1 + layer-2 GEMM fused
    k_gemm1<<<1024, 256, 0, stream>>>(x, W1, dinv, h1);
    k_agg1mm<<<2048, 256, 0, stream>>>(h1, W2, dinv, b1, off, eidx, h2);

    // layer-2 aggregation + log_softmax
    k_gather2<<<(N_NODES + 7) / 8, 256, 0, stream>>>(h2, out, off, eidx, dinv, b2, N_NODES);
}

// Round 9
// 184.070 us; speedup vs baseline: 3.1186x; 1.5868x over previous
//
#include <hip/hip_runtime.h>
#include <math.h>

#define N_NODES 100000
#define N_EDGES 600000
#define NC 41
#define NT (N_NODES / 16)            // 6250 exact 16-node tiles
#define NB ((N_NODES + 255) / 256)   // scan blocks (391)
#define G1B 1024                     // gemm1 blocks inside k_pre
#define CNTB ((N_EDGES + 255) / 256) // count blocks inside k_pre (2344)

typedef __attribute__((ext_vector_type(8))) short bf16x8;
typedef __attribute__((ext_vector_type(8))) unsigned short u16x8;
typedef __attribute__((ext_vector_type(4))) float f32x4;

static __device__ __forceinline__ unsigned short f2b(float f) {
    unsigned u = __float_as_uint(f);
    unsigned r = ((u >> 16) & 1u) + 0x7fffu;
    return (unsigned short)((u + r) >> 16);
}
static __device__ __forceinline__ float b2f(unsigned short s) {
    return __uint_as_float(((unsigned)s) << 16);
}
static __device__ __forceinline__ u16x8 zero8() {
    u16x8 z;
#pragma unroll
    for (int i = 0; i < 8; ++i) z[i] = 0;
    return z;
}

// ---------- k_pre: gemm1 (blocks 0..G1B-1, h1 UNSCALED) + degree count ----------
__global__ __launch_bounds__(256) void k_pre(const float* __restrict__ x,
                                             const float* __restrict__ W,
                                             unsigned short* __restrict__ h,
                                             const int* __restrict__ dst,
                                             int* __restrict__ cnt) {
    if (blockIdx.x >= G1B) {
        int e = (blockIdx.x - G1B) * 256 + threadIdx.x;
        if (e < N_EDGES) atomicAdd(&cnt[dst[e]], 1);
        return;
    }

    __shared__ unsigned short Wt[128 * 132];  // [n][k], padded
    int tid = threadIdx.x;
    for (int i = tid; i < 128 * 128; i += 256) {
        int k = i >> 7, n = i & 127;
        Wt[n * 132 + k] = f2b(W[i]);
    }
    __syncthreads();

    int l = tid & 63, w = tid >> 6;
    int lr = l & 15, g = l >> 4;

    bf16x8 bf[2][4];
#pragma unroll
    for (int c = 0; c < 2; ++c) {
        int n = (w * 2 + c) * 16 + lr;
#pragma unroll
        for (int kt = 0; kt < 4; ++kt) {
            const unsigned short* p = &Wt[n * 132 + kt * 32 + g * 4];
            short4 lo = *(const short4*)p;
            short4 hi = *(const short4*)(p + 16);
            bf16x8 f;
            f[0] = lo.x; f[1] = lo.y; f[2] = lo.z; f[3] = lo.w;
            f[4] = hi.x; f[5] = hi.y; f[6] = hi.z; f[7] = hi.w;
            bf[c][kt] = f;
        }
    }

    for (int t = blockIdx.x; t < NT; t += G1B) {
        int row = t * 16 + lr;
        const float4* xr = (const float4*)(x + (size_t)row * 128);
        f32x4 acc0 = {0.f, 0.f, 0.f, 0.f};
        f32x4 acc1 = {0.f, 0.f, 0.f, 0.f};
#pragma unroll
        for (int kt = 0; kt < 4; ++kt) {
            float4 alo = xr[kt * 8 + g];
            float4 ahi = xr[kt * 8 + 4 + g];
            bf16x8 a;
            a[0] = (short)f2b(alo.x); a[1] = (short)f2b(alo.y);
            a[2] = (short)f2b(alo.z); a[3] = (short)f2b(alo.w);
            a[4] = (short)f2b(ahi.x); a[5] = (short)f2b(ahi.y);
            a[6] = (short)f2b(ahi.z); a[7] = (short)f2b(ahi.w);
            acc0 = __builtin_amdgcn_mfma_f32_16x16x32_bf16(a, bf[0][kt], acc0, 0, 0, 0);
            acc1 = __builtin_amdgcn_mfma_f32_16x16x32_bf16(a, bf[1][kt], acc1, 0, 0, 0);
        }
        int c0 = (w * 2) * 16 + lr;
        int rbase = t * 16 + g * 4;
#pragma unroll
        for (int i = 0; i < 4; ++i) {
            h[(size_t)(rbase + i) * 128 + c0] = f2b(acc0[i]);
            h[(size_t)(rbase + i) * 128 + c0 + 16] = f2b(acc1[i]);
        }
    }
}

// ---------- blocksum + dinv ----------
__global__ __launch_bounds__(256) void k_blocksum(const int* __restrict__ cnt,
                                                  int* __restrict__ bsum,
                                                  float* __restrict__ dinv, int n) {
    __shared__ int tmp[256];
    int t = threadIdx.x, gid = blockIdx.x * 256 + t;
    int v = (gid < n) ? cnt[gid] : 0;
    if (gid < n) dinv[gid] = rsqrtf((float)(v + 1));  // +1 self-loop
    tmp[t] = v;
    __syncthreads();
    for (int d = 128; d; d >>= 1) {
        if (t < d) tmp[t] += tmp[t + d];
        __syncthreads();
    }
    if (t == 0) bsum[blockIdx.x] = tmp[0];
}

__global__ __launch_bounds__(512) void k_scanb(int* __restrict__ bsum, int nb) {
    __shared__ int tmp[512];
    int t = threadIdx.x;
    int v = (t < nb) ? bsum[t] : 0;
    tmp[t] = v;
    __syncthreads();
    for (int d = 1; d < 512; d <<= 1) {
        int u = (t >= d) ? tmp[t - d] : 0;
        __syncthreads();
        tmp[t] += u;
        __syncthreads();
    }
    if (t < nb) bsum[t] = tmp[t] - v;
}

__global__ __launch_bounds__(256) void k_scanfinal(int* __restrict__ cnt,
                                                   const int* __restrict__ bsum,
                                                   int* __restrict__ off, int n) {
    __shared__ int tmp[256];
    int t = threadIdx.x, gid = blockIdx.x * 256 + t;
    int v = (gid < n) ? cnt[gid] : 0;
    tmp[t] = v;
    __syncthreads();
    for (int d = 1; d < 256; d <<= 1) {
        int u = (t >= d) ? tmp[t - d] : 0;
        __syncthreads();
        tmp[t] += u;
        __syncthreads();
    }
    int ex = tmp[t] - v + bsum[blockIdx.x];
    if (gid < n) {
        off[gid] = ex;
        cnt[gid] = ex;  // becomes scatter cursor
    }
    if (gid == 0) off[n] = N_EDGES;
}

// ---------- scatter: pack {src, dinv[src]} into int2 CSR entries ----------
__global__ void k_scatter(const int* __restrict__ src, const int* __restrict__ dst,
                          const float* __restrict__ dinv,
                          int* __restrict__ cursor, int2* __restrict__ eidx, int E) {
    int e = blockIdx.x * blockDim.x + threadIdx.x;
    if (e >= E) return;
    int s = src[e];
    int d = dst[e];
    float ds = dinv[s];
    int pos = atomicAdd(&cursor[d], 1);
    eidx[pos] = make_int2(s, __float_as_int(ds));
}

// ---------- fused agg1 + GEMM2 (node-serial gather; dinv_s from packed eidx) ----------
__global__ __launch_bounds__(256, 8) void k_agg1mm(const unsigned short* __restrict__ h,
                                                   const float* __restrict__ W2,
                                                   const float* __restrict__ dinv,
                                                   const float* __restrict__ b1,
                                                   const int* __restrict__ off,
                                                   const int2* __restrict__ eidx,
                                                   unsigned short* __restrict__ h2) {
    __shared__ unsigned short Wt[48 * 132];   // W2^T bf16, padded
    __shared__ unsigned short rows[16 * 136]; // staged agg rows, padded
    int tid = threadIdx.x;
    for (int i = tid; i < 128 * 48; i += 256) {
        int k = i / 48, n = i % 48;
        Wt[n * 132 + k] = f2b((n < NC) ? W2[k * NC + n] : 0.f);
    }
    __syncthreads();

    int l = tid & 63, w = tid >> 6;
    int j = l & 15;                 // col-slice within node (8 cols each)
    int nloc = w * 4 + (l >> 4);    // node-local 0..15
    int lr = l & 15, g = l >> 4;

    for (int t = blockIdx.x; t < NT; t += gridDim.x) {
        int node = t * 16 + nloc;
        float di = dinv[node];
        float acc[8];
        {
            u16x8 v = *(const u16x8*)(h + (size_t)node * 128 + j * 8);
#pragma unroll
            for (int i = 0; i < 8; ++i) acc[i] = b2f(v[i]) * di;  // dinv_d * h[d]
        }
        int beg = off[node], end = off[node + 1];
        int e = beg;
        int2 p0 = (e < end) ? eidx[e] : make_int2(-1, 0);
        int2 p1 = (e + 1 < end) ? eidx[e + 1] : make_int2(-1, 0);
        u16x8 r0 = zero8(), r1 = zero8();
        if (p0.x >= 0) r0 = *(const u16x8*)(h + (size_t)p0.x * 128 + j * 8);
        if (p1.x >= 0) r1 = *(const u16x8*)(h + (size_t)p1.x * 128 + j * 8);
        while (p0.x >= 0) {
            int2 p2 = (e + 2 < end) ? eidx[e + 2] : make_int2(-1, 0);
            u16x8 r2 = zero8();
            if (p2.x >= 0) r2 = *(const u16x8*)(h + (size_t)p2.x * 128 + j * 8);
            float nm = __int_as_float(p0.y);
#pragma unroll
            for (int i = 0; i < 8; ++i) acc[i] = fmaf(b2f(r0[i]), nm, acc[i]);
            p0 = p1; p1 = p2; r0 = r1; r1 = r2; ++e;
        }
        // relu(di*acc + b1) -> LDS bf16 staging
        float4 blo = ((const float4*)b1)[j * 2];
        float4 bhi = ((const float4*)b1)[j * 2 + 1];
        u16x8 o;
        o[0] = f2b(fmaxf(acc[0] * di + blo.x, 0.f));
        o[1] = f2b(fmaxf(acc[1] * di + blo.y, 0.f));
        o[2] = f2b(fmaxf(acc[2] * di + blo.z, 0.f));
        o[3] = f2b(fmaxf(acc[3] * di + blo.w, 0.f));
        o[4] = f2b(fmaxf(acc[4] * di + bhi.x, 0.f));
        o[5] = f2b(fmaxf(acc[5] * di + bhi.y, 0.f));
        o[6] = f2b(fmaxf(acc[6] * di + bhi.z, 0.f));
        o[7] = f2b(fmaxf(acc[7] * di + bhi.w, 0.f));
        *(u16x8*)&rows[nloc * 136 + j * 8] = o;
        __syncthreads();

        if (w < 3) {  // col-tile w of 3 (48 cols)
            f32x4 a0 = {0.f, 0.f, 0.f, 0.f};
#pragma unroll
            for (int kt = 0; kt < 4; ++kt) {
                const unsigned short* pa = &rows[lr * 136 + kt * 32 + g * 4];
                short4 alo = *(const short4*)pa;
                short4 ahi = *(const short4*)(pa + 16);
                bf16x8 a;
                a[0] = alo.x; a[1] = alo.y; a[2] = alo.z; a[3] = alo.w;
                a[4] = ahi.x; a[5] = ahi.y; a[6] = ahi.z; a[7] = ahi.w;
                const unsigned short* pb = &Wt[(w * 16 + lr) * 132 + kt * 32 + g * 4];
                short4 wlo = *(const short4*)pb;
                short4 whi = *(const short4*)(pb + 16);
                bf16x8 bb;
                bb[0] = wlo.x; bb[1] = wlo.y; bb[2] = wlo.z; bb[3] = wlo.w;
                bb[4] = whi.x; bb[5] = whi.y; bb[6] = whi.z; bb[7] = whi.w;
                a0 = __builtin_amdgcn_mfma_f32_16x16x32_bf16(a, bb, a0, 0, 0, 0);
            }
            int rbase = t * 16 + g * 4;
#pragma unroll
            for (int i = 0; i < 4; ++i) {
                float dv = dinv[rbase + i];
                h2[(size_t)(rbase + i) * 64 + w * 16 + lr] = f2b(a0[i] * dv);
            }
        }
        __syncthreads();
    }
}

// ---------- gather2: out = log_softmax(di * (self + sum h2'[s]) + b2) ----------
// 2 nodes per wave; LDS-staged coalesced float4 output (12500 exact blocks).
__global__ __launch_bounds__(256, 8) void k_gather2(const unsigned short* __restrict__ h2,
                                                    float* __restrict__ out,
                                                    const int* __restrict__ off,
                                                    const int2* __restrict__ eidx,
                                                    const float* __restrict__ dinv,
                                                    const float* __restrict__ b2) {
    __shared__ float so[8 * NC + 8];  // 8 nodes x 41 outputs (+pad)
    int tid = threadIdx.x;
    int nloc = tid >> 5;
    int node = blockIdx.x * 8 + nloc;
    int l = tid & 31;
    int g = l >> 3, j = l & 7;
    bool act = (j < 6);
    float di = dinv[node];
    float acc[8];
#pragma unroll
    for (int i = 0; i < 8; ++i) acc[i] = 0.f;
    if (g == 0 && act) {
        u16x8 v = *(const u16x8*)(h2 + (size_t)node * 64 + j * 8);
#pragma unroll
        for (int i = 0; i < 8; ++i) acc[i] = b2f(v[i]);
    }
    int beg = off[node], end = off[node + 1];
    int e = beg + g;
    int s0 = (e < end) ? eidx[e].x : -1;
    int s1 = (e + 4 < end) ? eidx[e + 4].x : -1;
    u16x8 r0 = zero8(), r1 = zero8();
    if (s0 >= 0 && act) r0 = *(const u16x8*)(h2 + (size_t)s0 * 64 + j * 8);
    if (s1 >= 0 && act) r1 = *(const u16x8*)(h2 + (size_t)s1 * 64 + j * 8);
    while (s0 >= 0) {
        int s2 = (e + 8 < end) ? eidx[e + 8].x : -1;
        u16x8 r2 = zero8();
        if (s2 >= 0 && act) r2 = *(const u16x8*)(h2 + (size_t)s2 * 64 + j * 8);
#pragma unroll
        for (int i = 0; i < 8; ++i) acc[i] += b2f(r0[i]);
        s0 = s1; s1 = s2; r0 = r1; r1 = r2; e += 4;
    }
#pragma unroll
    for (int i = 0; i < 8; ++i) acc[i] += __shfl_xor(acc[i], 8);
#pragma unroll
    for (int i = 0; i < 8; ++i) acc[i] += __shfl_xor(acc[i], 16);
    int c0 = j * 8;
    float vv[8];
#pragma unroll
    for (int i = 0; i < 8; ++i)
        vv[i] = (act && c0 + i < NC) ? acc[i] * di + b2[c0 + i] : -INFINITY;
    float m = vv[0];
#pragma unroll
    for (int i = 1; i < 8; ++i) m = fmaxf(m, vv[i]);
#pragma unroll
    for (int o = 4; o; o >>= 1) m = fmaxf(m, __shfl_xor(m, o));
    float sm = 0.f;
#pragma unroll
    for (int i = 0; i < 8; ++i) sm += (act && c0 + i < NC) ? expf(vv[i] - m) : 0.f;
#pragma unroll
    for (int o = 4; o; o >>= 1) sm += __shfl_xor(sm, o);
    float lg = logf(sm);
    if (g == 0 && act) {
#pragma unroll
        for (int i = 0; i < 8; ++i) {
            int c = c0 + i;
            if (c < NC) so[nloc * NC + c] = vv[i] - m - lg;
        }
    }
    __syncthreads();
    // coalesced block write: 8 nodes x 41 floats = 328 floats = 82 float4
    float4* ob = (float4*)(out + (size_t)blockIdx.x * (8 * NC));
    const float4* sb = (const float4*)so;
    if (tid < 2 * NC) ob[tid] = sb[tid];
}

extern "C" void kernel_launch(void* const* d_in, const int* in_sizes, int n_in,
                              void* d_out, int out_size, void* d_ws, size_t ws_size,
                              hipStream_t stream) {
    const float* x  = (const float*)d_in[0];
    const float* W1 = (const float*)d_in[1];
    const float* b1 = (const float*)d_in[2];
    const float* W2 = (const float*)d_in[3];
    const float* b2 = (const float*)d_in[4];
    const int*   ei = (const int*)d_in[5];
    const int* src = ei;
    const int* dst = ei + N_EDGES;
    float* out = (float*)d_out;

    char* ws = (char*)d_ws;
    int*   cnt  = (int*)ws;                        // N ints
    int*   off  = cnt + N_NODES + 32;              // N+1 ints
    int*   bsum = off + N_NODES + 32;              // <=512 ints
    float* dinv = (float*)(bsum + 512);            // N floats
    int2*  eidx = (int2*)(dinv + N_NODES + 32);    // E int2 (4.8 MB)
    unsigned short* h1 = (unsigned short*)(ws + (8u << 20));   // N*128 bf16 (UNSCALED)
    unsigned short* h2 = h1 + (size_t)N_NODES * 128;           // N*64 bf16 (pre-scaled)

    // CSR build + layer-1 GEMM (count rides along in the same launch)
    hipMemsetAsync(cnt, 0, N_NODES * sizeof(int), stream);
    k_pre<<<G1B + CNTB, 256, 0, stream>>>(x, W1, h1, dst, cnt);
    k_blocksum<<<NB, 256, 0, stream>>>(cnt, bsum, dinv, N_NODES);
    k_scanb<<<1, 512, 0, stream>>>(bsum, NB);
    k_scanfinal<<<NB, 256, 0, stream>>>(cnt, bsum, off, N_NODES);
    k_scatter<<<CNTB, 256, 0, stream>>>(src, dst, dinv, cnt, eidx, N_EDGES);

    // fused agg1 + GEMM2
    k_agg1mm<<<2048, 256, 0, stream>>>(h1, W2, dinv, b1, off, eidx, h2);

    // layer-2 aggregation + log_softmax (coalesced output)
    k_gather2<<<N_NODES / 8, 256, 0, stream>>>(h2, out, off, eidx, dinv, b2);
}

// Round 10
// 178.157 us; speedup vs baseline: 3.2222x; 1.0332x over previous
//
#include <hip/hip_runtime.h>
#include <math.h>

#define N_NODES 100000
#define N_EDGES 600000
#define NC 41
#define NT (N_NODES / 16)            // 6250 exact 16-node tiles
#define NB ((N_NODES + 255) / 256)   // scan blocks (391)
#define G1B 1024                     // k_pre blocks (gemm1 + count tail)
#define CNTB ((N_EDGES + 255) / 256) // scatter blocks (2344)

typedef __attribute__((ext_vector_type(8))) short bf16x8;
typedef __attribute__((ext_vector_type(8))) unsigned short u16x8;
typedef __attribute__((ext_vector_type(4))) float f32x4;

static __device__ __forceinline__ unsigned short f2b(float f) {
    unsigned u = __float_as_uint(f);
    unsigned r = ((u >> 16) & 1u) + 0x7fffu;
    return (unsigned short)((u + r) >> 16);
}
static __device__ __forceinline__ float b2f(unsigned short s) {
    return __uint_as_float(((unsigned)s) << 16);
}
static __device__ __forceinline__ u16x8 zero8() {
    u16x8 z;
#pragma unroll
    for (int i = 0; i < 8; ++i) z[i] = 0;
    return z;
}

// ---------- k_pre: gemm1 (h1 UNSCALED) + grid-stride degree-count tail ----------
__global__ __launch_bounds__(256) void k_pre(const float* __restrict__ x,
                                             const float* __restrict__ W,
                                             unsigned short* __restrict__ h,
                                             const int* __restrict__ dst,
                                             int* __restrict__ cnt) {
    __shared__ unsigned short Wt[128 * 132];  // [n][k], padded
    int tid = threadIdx.x;
    for (int i = tid; i < 128 * 128; i += 256) {
        int k = i >> 7, n = i & 127;
        Wt[n * 132 + k] = f2b(W[i]);
    }
    __syncthreads();

    int l = tid & 63, w = tid >> 6;
    int lr = l & 15, g = l >> 4;

    bf16x8 bf[2][4];
#pragma unroll
    for (int c = 0; c < 2; ++c) {
        int n = (w * 2 + c) * 16 + lr;
#pragma unroll
        for (int kt = 0; kt < 4; ++kt) {
            const unsigned short* p = &Wt[n * 132 + kt * 32 + g * 4];
            short4 lo = *(const short4*)p;
            short4 hi = *(const short4*)(p + 16);
            bf16x8 f;
            f[0] = lo.x; f[1] = lo.y; f[2] = lo.z; f[3] = lo.w;
            f[4] = hi.x; f[5] = hi.y; f[6] = hi.z; f[7] = hi.w;
            bf[c][kt] = f;
        }
    }

    for (int t = blockIdx.x; t < NT; t += G1B) {
        int row = t * 16 + lr;
        const float4* xr = (const float4*)(x + (size_t)row * 128);
        f32x4 acc0 = {0.f, 0.f, 0.f, 0.f};
        f32x4 acc1 = {0.f, 0.f, 0.f, 0.f};
#pragma unroll
        for (int kt = 0; kt < 4; ++kt) {
            float4 alo = xr[kt * 8 + g];
            float4 ahi = xr[kt * 8 + 4 + g];
            bf16x8 a;
            a[0] = (short)f2b(alo.x); a[1] = (short)f2b(alo.y);
            a[2] = (short)f2b(alo.z); a[3] = (short)f2b(alo.w);
            a[4] = (short)f2b(ahi.x); a[5] = (short)f2b(ahi.y);
            a[6] = (short)f2b(ahi.z); a[7] = (short)f2b(ahi.w);
            acc0 = __builtin_amdgcn_mfma_f32_16x16x32_bf16(a, bf[0][kt], acc0, 0, 0, 0);
            acc1 = __builtin_amdgcn_mfma_f32_16x16x32_bf16(a, bf[1][kt], acc1, 0, 0, 0);
        }
        int c0 = (w * 2) * 16 + lr;
        int rbase = t * 16 + g * 4;
#pragma unroll
        for (int i = 0; i < 4; ++i) {
            h[(size_t)(rbase + i) * 128 + c0] = f2b(acc0[i]);
            h[(size_t)(rbase + i) * 128 + c0 + 16] = f2b(acc1[i]);
        }
    }

    // degree-count tail (grid-stride across the same 1024 blocks)
    for (int e = blockIdx.x * 256 + tid; e < N_EDGES; e += G1B * 256)
        atomicAdd(&cnt[dst[e]], 1);
}

// ---------- blocksum + dinv ----------
__global__ __launch_bounds__(256) void k_blocksum(const int* __restrict__ cnt,
                                                  int* __restrict__ bsum,
                                                  float* __restrict__ dinv, int n) {
    __shared__ int tmp[256];
    int t = threadIdx.x, gid = blockIdx.x * 256 + t;
    int v = (gid < n) ? cnt[gid] : 0;
    if (gid < n) dinv[gid] = rsqrtf((float)(v + 1));  // +1 self-loop
    tmp[t] = v;
    __syncthreads();
    for (int d = 128; d; d >>= 1) {
        if (t < d) tmp[t] += tmp[t + d];
        __syncthreads();
    }
    if (t == 0) bsum[blockIdx.x] = tmp[0];
}

__global__ __launch_bounds__(512) void k_scanb(int* __restrict__ bsum, int nb) {
    __shared__ int tmp[512];
    int t = threadIdx.x;
    int v = (t < nb) ? bsum[t] : 0;
    tmp[t] = v;
    __syncthreads();
    for (int d = 1; d < 512; d <<= 1) {
        int u = (t >= d) ? tmp[t - d] : 0;
        __syncthreads();
        tmp[t] += u;
        __syncthreads();
    }
    if (t < nb) bsum[t] = tmp[t] - v;
}

__global__ __launch_bounds__(256) void k_scanfinal(int* __restrict__ cnt,
                                                   const int* __restrict__ bsum,
                                                   int* __restrict__ off, int n) {
    __shared__ int tmp[256];
    int t = threadIdx.x, gid = blockIdx.x * 256 + t;
    int v = (gid < n) ? cnt[gid] : 0;
    tmp[t] = v;
    __syncthreads();
    for (int d = 1; d < 256; d <<= 1) {
        int u = (t >= d) ? tmp[t - d] : 0;
        __syncthreads();
        tmp[t] += u;
        __syncthreads();
    }
    int ex = tmp[t] - v + bsum[blockIdx.x];
    if (gid < n) {
        off[gid] = ex;
        cnt[gid] = ex;  // becomes scatter cursor
    }
    if (gid == 0) off[n] = N_EDGES;
}

// ---------- scatter: pack {src, dinv[src]} into int2 CSR entries ----------
__global__ void k_scatter(const int* __restrict__ src, const int* __restrict__ dst,
                          const float* __restrict__ dinv,
                          int* __restrict__ cursor, int2* __restrict__ eidx, int E) {
    int e = blockIdx.x * blockDim.x + threadIdx.x;
    if (e >= E) return;
    int s = src[e];
    int d = dst[e];
    float ds = dinv[s];
    int pos = atomicAdd(&cursor[d], 1);
    eidx[pos] = make_int2(s, __float_as_int(ds));
}

// ---------- fused agg1 + GEMM2 (node-serial gather; dinv_s from packed eidx) ----------
__global__ __launch_bounds__(256, 8) void k_agg1mm(const unsigned short* __restrict__ h,
                                                   const float* __restrict__ W2,
                                                   const float* __restrict__ dinv,
                                                   const float* __restrict__ b1,
                                                   const int* __restrict__ off,
                                                   const int2* __restrict__ eidx,
                                                   unsigned short* __restrict__ h2) {
    __shared__ unsigned short Wt[48 * 132];   // W2^T bf16, padded
    __shared__ unsigned short rows[16 * 136]; // staged agg rows, padded
    int tid = threadIdx.x;
    for (int i = tid; i < 128 * 48; i += 256) {
        int k = i / 48, n = i % 48;
        Wt[n * 132 + k] = f2b((n < NC) ? W2[k * NC + n] : 0.f);
    }
    __syncthreads();

    int l = tid & 63, w = tid >> 6;
    int j = l & 15;                 // col-slice within node (8 cols each)
    int nloc = w * 4 + (l >> 4);    // node-local 0..15
    int lr = l & 15, g = l >> 4;

    for (int t = blockIdx.x; t < NT; t += gridDim.x) {
        int node = t * 16 + nloc;
        float di = dinv[node];
        float acc[8];
        {
            u16x8 v = *(const u16x8*)(h + (size_t)node * 128 + j * 8);
#pragma unroll
            for (int i = 0; i < 8; ++i) acc[i] = b2f(v[i]) * di;  // dinv_d * h[d]
        }
        int beg = off[node], end = off[node + 1];
        int e = beg;
        int2 p0 = (e < end) ? eidx[e] : make_int2(-1, 0);
        int2 p1 = (e + 1 < end) ? eidx[e + 1] : make_int2(-1, 0);
        u16x8 r0 = zero8(), r1 = zero8();
        if (p0.x >= 0) r0 = *(const u16x8*)(h + (size_t)p0.x * 128 + j * 8);
        if (p1.x >= 0) r1 = *(const u16x8*)(h + (size_t)p1.x * 128 + j * 8);
        while (p0.x >= 0) {
            int2 p2 = (e + 2 < end) ? eidx[e + 2] : make_int2(-1, 0);
            u16x8 r2 = zero8();
            if (p2.x >= 0) r2 = *(const u16x8*)(h + (size_t)p2.x * 128 + j * 8);
            float nm = __int_as_float(p0.y);
#pragma unroll
            for (int i = 0; i < 8; ++i) acc[i] = fmaf(b2f(r0[i]), nm, acc[i]);
            p0 = p1; p1 = p2; r0 = r1; r1 = r2; ++e;
        }
        // relu(di*acc + b1) -> LDS bf16 staging
        float4 blo = ((const float4*)b1)[j * 2];
        float4 bhi = ((const float4*)b1)[j * 2 + 1];
        u16x8 o;
        o[0] = f2b(fmaxf(acc[0] * di + blo.x, 0.f));
        o[1] = f2b(fmaxf(acc[1] * di + blo.y, 0.f));
        o[2] = f2b(fmaxf(acc[2] * di + blo.z, 0.f));
        o[3] = f2b(fmaxf(acc[3] * di + blo.w, 0.f));
        o[4] = f2b(fmaxf(acc[4] * di + bhi.x, 0.f));
        o[5] = f2b(fmaxf(acc[5] * di + bhi.y, 0.f));
        o[6] = f2b(fmaxf(acc[6] * di + bhi.z, 0.f));
        o[7] = f2b(fmaxf(acc[7] * di + bhi.w, 0.f));
        *(u16x8*)&rows[nloc * 136 + j * 8] = o;
        __syncthreads();

        if (w < 3) {  // col-tile w of 3 (48 cols)
            f32x4 a0 = {0.f, 0.f, 0.f, 0.f};
#pragma unroll
            for (int kt = 0; kt < 4; ++kt) {
                const unsigned short* pa = &rows[lr * 136 + kt * 32 + g * 4];
                short4 alo = *(const short4*)pa;
                short4 ahi = *(const short4*)(pa + 16);
                bf16x8 a;
                a[0] = alo.x; a[1] = alo.y; a[2] = alo.z; a[3] = alo.w;
                a[4] = ahi.x; a[5] = ahi.y; a[6] = ahi.z; a[7] = ahi.w;
                const unsigned short* pb = &Wt[(w * 16 + lr) * 132 + kt * 32 + g * 4];
                short4 wlo = *(const short4*)pb;
                short4 whi = *(const short4*)(pb + 16);
                bf16x8 bb;
                bb[0] = wlo.x; bb[1] = wlo.y; bb[2] = wlo.z; bb[3] = wlo.w;
                bb[4] = whi.x; bb[5] = whi.y; bb[6] = whi.z; bb[7] = whi.w;
                a0 = __builtin_amdgcn_mfma_f32_16x16x32_bf16(a, bb, a0, 0, 0, 0);
            }
            int rbase = t * 16 + g * 4;
#pragma unroll
            for (int i = 0; i < 4; ++i) {
                float dv = dinv[rbase + i];
                h2[(size_t)(rbase + i) * 64 + w * 16 + lr] = f2b(a0[i] * dv);
            }
        }
        __syncthreads();
    }
}

// ---------- gather2: out = log_softmax(di * (self + sum h2'[s]) + b2) ----------
// 2 nodes per wave; LDS-staged coalesced float4 output (12500 exact blocks).
__global__ __launch_bounds__(256, 8) void k_gather2(const unsigned short* __restrict__ h2,
                                                    float* __restrict__ out,
                                                    const int* __restrict__ off,
                                                    const int2* __restrict__ eidx,
                                                    const float* __restrict__ dinv,
                                                    const float* __restrict__ b2) {
    __shared__ float so[8 * NC + 8];  // 8 nodes x 41 outputs (+pad)
    int tid = threadIdx.x;
    int nloc = tid >> 5;
    int node = blockIdx.x * 8 + nloc;
    int l = tid & 31;
    int g = l >> 3, j = l & 7;
    bool act = (j < 6);
    float di = dinv[node];
    float acc[8];
#pragma unroll
    for (int i = 0; i < 8; ++i) acc[i] = 0.f;
    if (g == 0 && act) {
        u16x8 v = *(const u16x8*)(h2 + (size_t)node * 64 + j * 8);
#pragma unroll
        for (int i = 0; i < 8; ++i) acc[i] = b2f(v[i]);
    }
    int beg = off[node], end = off[node + 1];
    int e = beg + g;
    int s0 = (e < end) ? eidx[e].x : -1;
    int s1 = (e + 4 < end) ? eidx[e + 4].x : -1;
    u16x8 r0 = zero8(), r1 = zero8();
    if (s0 >= 0 && act) r0 = *(const u16x8*)(h2 + (size_t)s0 * 64 + j * 8);
    if (s1 >= 0 && act) r1 = *(const u16x8*)(h2 + (size_t)s1 * 64 + j * 8);
    while (s0 >= 0) {
        int s2 = (e + 8 < end) ? eidx[e + 8].x : -1;
        u16x8 r2 = zero8();
        if (s2 >= 0 && act) r2 = *(const u16x8*)(h2 + (size_t)s2 * 64 + j * 8);
#pragma unroll
        for (int i = 0; i < 8; ++i) acc[i] += b2f(r0[i]);
        s0 = s1; s1 = s2; r0 = r1; r1 = r2; e += 4;
    }
#pragma unroll
    for (int i = 0; i < 8; ++i) acc[i] += __shfl_xor(acc[i], 8);
#pragma unroll
    for (int i = 0; i < 8; ++i) acc[i] += __shfl_xor(acc[i], 16);
    int c0 = j * 8;
    float vv[8];
#pragma unroll
    for (int i = 0; i < 8; ++i)
        vv[i] = (act && c0 + i < NC) ? acc[i] * di + b2[c0 + i] : -INFINITY;
    float m = vv[0];
#pragma unroll
    for (int i = 1; i < 8; ++i) m = fmaxf(m, vv[i]);
#pragma unroll
    for (int o = 4; o; o >>= 1) m = fmaxf(m, __shfl_xor(m, o));
    float sm = 0.f;
#pragma unroll
    for (int i = 0; i < 8; ++i) sm += (act && c0 + i < NC) ? expf(vv[i] - m) : 0.f;
#pragma unroll
    for (int o = 4; o; o >>= 1) sm += __shfl_xor(sm, o);
    float lg = logf(sm);
    if (g == 0 && act) {
#pragma unroll
        for (int i = 0; i < 8; ++i) {
            int c = c0 + i;
            if (c < NC) so[nloc * NC + c] = vv[i] - m - lg;
        }
    }
    __syncthreads();
    // coalesced block write: 8 nodes x 41 floats = 328 floats = 82 float4
    float4* ob = (float4*)(out + (size_t)blockIdx.x * (8 * NC));
    const float4* sb = (const float4*)so;
    if (tid < 2 * NC) ob[tid] = sb[tid];
}

extern "C" void kernel_launch(void* const* d_in, const int* in_sizes, int n_in,
                              void* d_out, int out_size, void* d_ws, size_t ws_size,
                              hipStream_t stream) {
    const float* x  = (const float*)d_in[0];
    const float* W1 = (const float*)d_in[1];
    const float* b1 = (const float*)d_in[2];
    const float* W2 = (const float*)d_in[3];
    const float* b2 = (const float*)d_in[4];
    const int*   ei = (const int*)d_in[5];
    const int* src = ei;
    const int* dst = ei + N_EDGES;
    float* out = (float*)d_out;

    char* ws = (char*)d_ws;
    int*   cnt  = (int*)ws;                        // N ints
    int*   off  = cnt + N_NODES + 32;              // N+1 ints
    int*   bsum = off + N_NODES + 32;              // <=512 ints
    float* dinv = (float*)(bsum + 512);            // N floats
    int2*  eidx = (int2*)(dinv + N_NODES + 32);    // E int2 (4.8 MB)
    unsigned short* h1 = (unsigned short*)(ws + (8u << 20));   // N*128 bf16 (UNSCALED)
    unsigned short* h2 = h1 + (size_t)N_NODES * 128;           // N*64 bf16 (pre-scaled)

    // CSR build + layer-1 GEMM (count tail inside k_pre's 1024 blocks)
    hipMemsetAsync(cnt, 0, N_NODES * sizeof(int), stream);
    k_pre<<<G1B, 256, 0, stream>>>(x, W1, h1, dst, cnt);
    k_blocksum<<<NB, 256, 0, stream>>>(cnt, bsum, dinv, N_NODES);
    k_scanb<<<1, 512, 0, stream>>>(bsum, NB);
    k_scanfinal<<<NB, 256, 0, stream>>>(cnt, bsum, off, N_NODES);
    k_scatter<<<CNTB, 256, 0, stream>>>(src, dst, dinv, cnt, eidx, N_EDGES);

    // fused agg1 + GEMM2
    k_agg1mm<<<2048, 256, 0, stream>>>(h1, W2, dinv, b1, off, eidx, h2);

    // layer-2 aggregation + log_softmax (coalesced output)
    k_gather2<<<N_NODES / 8, 256, 0, stream>>>(h2, out, off, eidx, dinv, b2);
}